// Round 9
// baseline (133.976 us; speedup 1.0000x reference)
//
#include <hip/hip_runtime.h>
#include <hip/hip_bf16.h>

#define MM 4096
#define NN 512
#define RR 32

__device__ __forceinline__ float softplus_f(float x) {
    return x > 20.0f ? x : log1pf(__expf(x));
}

__device__ __forceinline__ int bitrev6(int l) {
    return ((l & 1) << 5) | ((l & 2) << 3) | ((l & 4) << 1) |
           ((l & 8) >> 1) | ((l & 16) >> 3) | ((l & 32) >> 5);
}

// In-register 64-point DIF FFT across the 64 lanes of a wave.
// Input: lane l holds x[l]. Output: lane l holds X[bitrev6(l)].
__device__ __forceinline__ void wave_fft64(float& xr, float& xi) {
#pragma unroll
    for (int s = 32; s >= 1; s >>= 1) {
        const float pr = __shfl_xor(xr, s, 64);
        const float pi = __shfl_xor(xi, s, 64);
        const int   lane = threadIdx.x & 63;
        const bool  hi = (lane & s) != 0;
        const float ur = xr + pr, ui = xi + pi;
        const float vr = pr - xr, vi = pi - xi;
        const int   j  = lane & (s - 1);
        const float rev = (float)j * (1.0f / (float)(2 * s));   // [0, 0.5)
        const float ct = __builtin_amdgcn_cosf(rev);
        const float st = __builtin_amdgcn_sinf(rev);
        const float wr = fmaf(vr, ct,   vi * st);   // v * (ct - i st)
        const float wi = fmaf(vi, ct, -(vr * st));
        xr = hi ? wr : ur;
        xi = hi ? wi : ui;
    }
}

// Device-scope grid barrier. ctr zeroed per launch via captured memset.
// Release fence (L2 writeback) -> arrive -> coherent RMW spin -> acquire
// fence (cache invalidate). Co-residency guaranteed: 512 blocks, 2/CU.
__device__ __forceinline__ void grid_barrier(unsigned int* ctr, unsigned int target) {
    __syncthreads();
    if (threadIdx.x == 0) {
        __threadfence();                          // release: writeback
        atomicAdd(ctr, 1u);
        while (atomicAdd(ctr, 0u) < target) { }   // coherent RMW read
        __threadfence();                          // acquire: invalidate
    }
    __syncthreads();
}

// ---------------------------------------------------------------------------
// Fused single-dispatch kernel: FFT step1 | barrier | FFT step2 | barrier |
// Hermitian-pair main evaluation. 512 blocks x 256 threads.
// ---------------------------------------------------------------------------
__global__ __launch_bounds__(256, 2) void shiftnmf_fused(
        const float* __restrict__ W, const float* __restrict__ tau,
        const float* __restrict__ H, float* __restrict__ out,
        float2* __restrict__ zbuf, float2* __restrict__ hft,
        unsigned int* __restrict__ bar) {
    const int bid = blockIdx.x;
    const int tid = threadIdx.x;

    // ---------------- Phase 1: FFT-64 over n2, twiddle, transpose ----------
    {
        const int wave = (bid * 256 + tid) >> 6;   // 0..2047
        const int lane = tid & 63;                 // n2
        const int d    = wave >> 6;                // 0..31
        const int n1   = wave & 63;                // 0..63

        float xr = softplus_f(H[(size_t)d * MM + n1 + 64 * lane]);
        float xi = 0.0f;
        wave_fft64(xr, xi);

        const int k2 = bitrev6(lane);
        const float rev = (float)(n1 * k2) * (1.0f / 4096.0f);   // [0,1)
        const float ct = __builtin_amdgcn_cosf(rev);
        const float st = __builtin_amdgcn_sinf(rev);
        const float zr = fmaf(xr, ct,   xi * st);
        const float zi = fmaf(xi, ct, -(xr * st));
        zbuf[(size_t)d * MM + k2 * 64 + n1] = make_float2(zr, zi);
    }
    grid_barrier(bar, gridDim.x);

    // ---------------- Phase 2: FFT-64 over n1, scatter ---------------------
    {
        const int wave = (bid * 256 + tid) >> 6;
        const int lane = tid & 63;                 // n1
        const int d    = wave >> 6;
        const int k2   = wave & 63;

        const float2 z = zbuf[(size_t)d * MM + k2 * 64 + lane];
        float xr = z.x, xi = z.y;
        wave_fft64(xr, xi);

        const int k1 = bitrev6(lane);
        hft[(size_t)d * MM + k2 + 64 * k1] = make_float2(xr, xi);
    }
    grid_barrier(bar + 32, gridDim.x);

    // ---------------- Phase 3: main (Hermitian-pair, R6-proven body) -------
    __shared__ float spw_s[8][RR];
    __shared__ float tf_s[8][RR];
    __shared__ float cu_s[8][RR];
    __shared__ float su_s[8][RR];
    __shared__ float h2048_s[RR];

    const int bx = bid & 7;          // m-tile: mb in [0, 2048)
    const int by = bid >> 3;         // n-tile
    const int mb = bx * 256;
    const int nb = by * 8;

    {
        const int nl = tid >> 5;
        const int dd = tid & 31;
        const float w = W[(size_t)(nb + nl) * RR + dd];
        const float t = tau[(size_t)(nb + nl) * RR + dd];
        spw_s[nl][dd] = softplus_f(w);
        tf_s[nl][dd]  = t * (1.0f / (float)MM);
        const float fr = t - floorf(t);                // frac(tau)
        cu_s[nl][dd] =  __builtin_amdgcn_cosf(fr);     // Re e^{-2pi i tau}
        su_s[nl][dd] = -__builtin_amdgcn_sinf(fr);     // Im e^{-2pi i tau}
    }
    if (tid < RR) h2048_s[tid] = hft[(size_t)tid * MM + 2048].x;
    __syncthreads();

    const int g  = tid >> 5;
    const int ml = tid & 31;
    const int n  = nb + g;
    const float m0f = (float)(mb + ml);
    const float2* hcol = hft + mb + ml;

    float accm[8], accp[8];
#pragma unroll
    for (int k = 0; k < 8; ++k) { accm[k] = 0.0f; accp[k] = 0.0f; }

    float2 hc[8], hn[8];
#pragma unroll
    for (int k = 0; k < 8; ++k) hc[k] = hcol[32 * k];

    for (int d = 0; d < RR; ++d) {
        const float2* hnp = hcol + (size_t)((d + 1 < RR) ? d + 1 : d) * MM;
#pragma unroll
        for (int k = 0; k < 8; ++k) hn[k] = hnp[32 * k];

        const float A  = spw_s[g][d];
        const float tf = tf_s[g][d];
        const float ru = cu_s[g][d];
        const float iu = su_s[g][d];

        float r0 = tf * m0f;   r0 -= floorf(r0);
        float dl = tf * 32.0f; dl -= floorf(dl);
        const float c0 = __builtin_amdgcn_cosf(r0);
        const float s0 = __builtin_amdgcn_sinf(r0);
        const float cd = __builtin_amdgcn_cosf(dl);
        const float sd = __builtin_amdgcn_sinf(dl);
        float ca = A * c0, sa = A * s0;               // phasor, even k
        float cb = ca * cd - sa * sd;                 // phasor, odd k
        float sb = sa * cd + ca * sd;
        const float c2 = fmaf(-2.0f * sd, sd, 1.0f);  // rotate by 2*delta
        const float s2 = 2.0f * sd * cd;

#pragma unroll
        for (int t = 0; t < 4; ++t) {
            const float2 h0 = hc[2 * t];
            const float2 h1 = hc[2 * t + 1];
            {
                const float rz = fmaf(ca, h0.x,   sa * h0.y);
                const float iz = fmaf(ca, h0.y, -(sa * h0.x));
                accm[2 * t]     += rz;
                accp[2 * t]      = fmaf(ru, rz, fmaf(iu, iz, accp[2 * t]));
            }
            {
                const float rz = fmaf(cb, h1.x,   sb * h1.y);
                const float iz = fmaf(cb, h1.y, -(sb * h1.x));
                accm[2 * t + 1] += rz;
                accp[2 * t + 1]  = fmaf(ru, rz, fmaf(iu, iz, accp[2 * t + 1]));
            }
            if (t < 3) {
                const float can = fmaf(ca, c2, -(sa * s2));
                const float san = fmaf(sa, c2,  (ca * s2));
                const float cbn = fmaf(cb, c2, -(sb * s2));
                const float sbn = fmaf(sb, c2,  (cb * s2));
                ca = can; sa = san; cb = cbn; sb = sbn;
            }
        }
#pragma unroll
        for (int k = 0; k < 8; ++k) hc[k] = hn[k];
    }

    float* orow = out + (size_t)n * MM;
#pragma unroll
    for (int k = 0; k < 8; ++k) {
        const int m = mb + ml + 32 * k;       // [0, 2047]
        orow[m] = accm[k];
        if (m != 0) orow[MM - m] = accp[k];   // [2049, 4095]
    }

    if (bx == 0 && ml == 0) {   // Nyquist column m = 2048 (real bin)
        float acc = 0.0f;
        for (int d = 0; d < RR; ++d) {
            float r = tf_s[g][d] * 2048.0f;
            r -= floorf(r);
            acc = fmaf(spw_s[g][d] * h2048_s[d], __builtin_amdgcn_cosf(r), acc);
        }
        orow[2048] = acc;
    }
}

// ---------------------------------------------------------------------------
// Complex-output hedge path (never taken in practice): R8 kernels.
// ---------------------------------------------------------------------------
__global__ __launch_bounds__(256) void fft64_step1(const float* __restrict__ H,
                                                   float2* __restrict__ zbuf) {
    const int wave = (blockIdx.x * 256 + threadIdx.x) >> 6;
    const int lane = threadIdx.x & 63;
    const int d    = wave >> 6;
    const int n1   = wave & 63;
    float xr = softplus_f(H[(size_t)d * MM + n1 + 64 * lane]);
    float xi = 0.0f;
    wave_fft64(xr, xi);
    const int k2 = bitrev6(lane);
    const float rev = (float)(n1 * k2) * (1.0f / 4096.0f);
    const float ct = __builtin_amdgcn_cosf(rev);
    const float st = __builtin_amdgcn_sinf(rev);
    zbuf[(size_t)d * MM + k2 * 64 + n1] =
        make_float2(fmaf(xr, ct, xi * st), fmaf(xi, ct, -(xr * st)));
}

__global__ __launch_bounds__(256) void fft64_step2(const float2* __restrict__ zbuf,
                                                   float2* __restrict__ hft) {
    const int wave = (blockIdx.x * 256 + threadIdx.x) >> 6;
    const int lane = threadIdx.x & 63;
    const int d    = wave >> 6;
    const int k2   = wave & 63;
    const float2 z = zbuf[(size_t)d * MM + k2 * 64 + lane];
    float xr = z.x, xi = z.y;
    wave_fft64(xr, xi);
    hft[(size_t)d * MM + k2 + 64 * bitrev6(lane)] = make_float2(xr, xi);
}

__global__ __launch_bounds__(256) void shiftnmf_cplx(const float* __restrict__ W,
                                                     const float* __restrict__ tau,
                                                     const float2* __restrict__ hft,
                                                     float* __restrict__ out) {
    __shared__ float spw_s[16][RR];
    __shared__ float tau_s[16][RR];
    const int tid = threadIdx.x;
    const int mb  = blockIdx.x * 256;
    const int nb  = blockIdx.y * 16;
    for (int idx = tid; idx < 16 * RR; idx += 256) {
        const int nl = idx >> 5;
        const int dd = idx & 31;
        spw_s[nl][dd] = softplus_f(W[(size_t)(nb + nl) * RR + dd]);
        tau_s[nl][dd] = tau[(size_t)(nb + nl) * RR + dd] * (1.0f / (float)MM);
    }
    __syncthreads();
    const int g  = tid >> 5;
    const int ml = tid & 31;
    const int n0 = g * 2;
    const float m0f = (float)(mb + ml);
    const float2* hcol = hft + mb + ml;
    float accR[2][8], accI[2][8];
#pragma unroll
    for (int j = 0; j < 2; ++j)
#pragma unroll
        for (int k = 0; k < 8; ++k) { accR[j][k] = 0.0f; accI[j][k] = 0.0f; }
    float2 hc[8], hn[8];
#pragma unroll
    for (int k = 0; k < 8; ++k) hc[k] = hcol[32 * k];
    for (int d = 0; d < RR; ++d) {
        const float2* hnp = hcol + (size_t)((d + 1 < RR) ? d + 1 : d) * MM;
#pragma unroll
        for (int k = 0; k < 8; ++k) hn[k] = hnp[32 * k];
#pragma unroll
        for (int j = 0; j < 2; ++j) {
            const float A  = spw_s[n0 + j][d];
            const float tf = tau_s[n0 + j][d];
            float r0 = tf * m0f;  r0 -= floorf(r0);
            float dl = tf * 32.0f; dl -= floorf(dl);
            const float c0 = __builtin_amdgcn_cosf(r0);
            const float s0 = __builtin_amdgcn_sinf(r0);
            const float cd = __builtin_amdgcn_cosf(dl);
            const float sd = __builtin_amdgcn_sinf(dl);
            float ca = A * c0, sa = A * s0;
            float cb = ca * cd - sa * sd;
            float sb = sa * cd + ca * sd;
            const float c2 = fmaf(-2.0f * sd, sd, 1.0f);
            const float s2 = 2.0f * sd * cd;
#pragma unroll
            for (int t4 = 0; t4 < 4; ++t4) {
                const float2 h0 = hc[2 * t4];
                const float2 h1 = hc[2 * t4 + 1];
                accR[j][2*t4]   = fmaf(ca, h0.x, fmaf(sa, h0.y, accR[j][2*t4]));
                accR[j][2*t4+1] = fmaf(cb, h1.x, fmaf(sb, h1.y, accR[j][2*t4+1]));
                accI[j][2*t4]   = fmaf(ca, h0.y, fmaf(-sa, h0.x, accI[j][2*t4]));
                accI[j][2*t4+1] = fmaf(cb, h1.y, fmaf(-sb, h1.x, accI[j][2*t4+1]));
                if (t4 < 3) {
                    const float can = fmaf(ca, c2, -(sa * s2));
                    const float san = fmaf(sa, c2,  (ca * s2));
                    const float cbn = fmaf(cb, c2, -(sb * s2));
                    const float sbn = fmaf(sb, c2,  (cb * s2));
                    ca = can; sa = san; cb = cbn; sb = sbn;
                }
            }
        }
#pragma unroll
        for (int k = 0; k < 8; ++k) hc[k] = hn[k];
    }
#pragma unroll
    for (int j = 0; j < 2; ++j) {
        float2* orow = (float2*)out + (size_t)(nb + n0 + j) * MM + mb + ml;
#pragma unroll
        for (int k = 0; k < 8; ++k)
            orow[32 * k] = make_float2(accR[j][k], accI[j][k]);
    }
}

extern "C" void kernel_launch(void* const* d_in, const int* in_sizes, int n_in,
                              void* d_out, int out_size, void* d_ws, size_t ws_size,
                              hipStream_t stream) {
    const float* W   = (const float*)d_in[0];   // (512, 32)
    const float* H   = (const float*)d_in[1];   // (32, 4096)
    const float* tau = (const float*)d_in[2];   // (512, 32)

    const size_t hft_bytes = (size_t)RR * MM * sizeof(float2);  // 1 MB
    if (ws_size < 2 * hft_bytes + 4096) return;   // safe bail
    float2* zbuf = (float2*)d_ws;                                // 1 MB
    float2* hft  = zbuf + (size_t)RR * MM;                       // 1 MB
    unsigned int* bar = (unsigned int*)((char*)d_ws + 2 * hft_bytes);

    if (out_size >= 2 * NN * MM) {
        fft64_step1<<<512, 256, 0, stream>>>(H, zbuf);
        fft64_step2<<<512, 256, 0, stream>>>(zbuf, hft);
        dim3 grid(MM / 256, NN / 16);
        shiftnmf_cplx<<<grid, 256, 0, stream>>>(W, tau, hft, (float*)d_out);
    } else {
        // zero the two barrier counters each call (captured into the graph)
        hipMemsetAsync(bar, 0, 256, stream);
        shiftnmf_fused<<<512, 256, 0, stream>>>(W, tau, H, (float*)d_out,
                                                zbuf, hft, bar);
    }
}

// Round 10
// 51.249 us; speedup vs baseline: 2.6142x; 2.6142x over previous
//
#include <hip/hip_runtime.h>
#include <hip/hip_bf16.h>

#define MM 4096
#define NN 512
#define RR 32

__device__ __forceinline__ float softplus_f(float x) {
    return x > 20.0f ? x : log1pf(__expf(x));
}

__device__ __forceinline__ int bitrev6(int l) {
    return ((l & 1) << 5) | ((l & 2) << 3) | ((l & 4) << 1) |
           ((l & 8) >> 1) | ((l & 16) >> 3) | ((l & 32) >> 5);
}

// In-register 64-point DIF FFT across the 64 lanes of a wave.
// Input: lane l holds x[l]. Output: lane l holds X[bitrev6(l)].
__device__ __forceinline__ void wave_fft64(float& xr, float& xi) {
#pragma unroll
    for (int s = 32; s >= 1; s >>= 1) {
        const float pr = __shfl_xor(xr, s, 64);
        const float pi = __shfl_xor(xi, s, 64);
        const int   lane = threadIdx.x & 63;
        const bool  hi = (lane & s) != 0;
        const float ur = xr + pr, ui = xi + pi;
        const float vr = pr - xr, vi = pi - xi;
        const int   j  = lane & (s - 1);
        const float rev = (float)j * (1.0f / (float)(2 * s));   // [0, 0.5)
        const float ct = __builtin_amdgcn_cosf(rev);
        const float st = __builtin_amdgcn_sinf(rev);
        const float wr = fmaf(vr, ct,   vi * st);   // v * (ct - i st)
        const float wi = fmaf(vi, ct, -(vr * st));
        xr = hi ? wr : ur;
        xi = hi ? wi : ui;
    }
}

// ---------------------------------------------------------------------------
// FFT step 1 (R8-proven): FFT-64 over n2, twiddle, transposed store.
// ---------------------------------------------------------------------------
__global__ __launch_bounds__(256) void fft64_step1(const float* __restrict__ H,
                                                   float2* __restrict__ zbuf) {
    const int wave = (blockIdx.x * 256 + threadIdx.x) >> 6;   // 0..2047
    const int lane = threadIdx.x & 63;                        // n2
    const int d    = wave >> 6;                               // 0..31
    const int n1   = wave & 63;                               // 0..63
    float xr = softplus_f(H[(size_t)d * MM + n1 + 64 * lane]);
    float xi = 0.0f;
    wave_fft64(xr, xi);
    const int k2 = bitrev6(lane);
    const float rev = (float)(n1 * k2) * (1.0f / 4096.0f);    // [0,1)
    const float ct = __builtin_amdgcn_cosf(rev);
    const float st = __builtin_amdgcn_sinf(rev);
    zbuf[(size_t)d * MM + k2 * 64 + n1] =
        make_float2(fmaf(xr, ct, xi * st), fmaf(xi, ct, -(xr * st)));
}

// ---------------------------------------------------------------------------
// FFT step 2 (R8-proven): FFT-64 over n1 (contiguous), scatter.
// ---------------------------------------------------------------------------
__global__ __launch_bounds__(256) void fft64_step2(const float2* __restrict__ zbuf,
                                                   float2* __restrict__ hft) {
    const int wave = (blockIdx.x * 256 + threadIdx.x) >> 6;
    const int lane = threadIdx.x & 63;                        // n1
    const int d    = wave >> 6;
    const int k2   = wave & 63;
    const float2 z = zbuf[(size_t)d * MM + k2 * 64 + lane];
    float xr = z.x, xi = z.y;
    wave_fft64(xr, xi);
    hft[(size_t)d * MM + k2 + 64 * bitrev6(lane)] = make_float2(xr, xi);
}

// ---------------------------------------------------------------------------
// Main kernel (real output, Hermitian-pair), latency-hiding version:
//   - K=4 m-values/thread, 128-col tiles -> grid (16,64) = 1024 blocks
//     = 4 waves/SIMD (2x round 6 occupancy).
//   - depth-2 register prefetch of hft rows (3 named buffers, d-loop fully
//     unrolled so all buffer indices are compile-time constants).
// Math body identical to the R6/R8-proven Hermitian formulation.
// ---------------------------------------------------------------------------
__global__ __launch_bounds__(256) void shiftnmf_real(const float* __restrict__ W,
                                                     const float* __restrict__ tau,
                                                     const float2* __restrict__ hft,
                                                     float* __restrict__ out) {
    __shared__ float spw_s[8][RR];
    __shared__ float tf_s[8][RR];
    __shared__ float cu_s[8][RR];
    __shared__ float su_s[8][RR];
    __shared__ float h2048_s[RR];

    const int tid = threadIdx.x;
    const int mb  = blockIdx.x * 128;      // [0, 2048)
    const int nb  = blockIdx.y * 8;

    {
        const int nl = tid >> 5;
        const int dd = tid & 31;
        const float w = W[(size_t)(nb + nl) * RR + dd];
        const float t = tau[(size_t)(nb + nl) * RR + dd];
        spw_s[nl][dd] = softplus_f(w);
        tf_s[nl][dd]  = t * (1.0f / (float)MM);
        const float fr = t - floorf(t);                // frac(tau)
        cu_s[nl][dd] =  __builtin_amdgcn_cosf(fr);     // Re e^{-2pi i tau}
        su_s[nl][dd] = -__builtin_amdgcn_sinf(fr);     // Im e^{-2pi i tau}
    }
    if (tid < RR) h2048_s[tid] = hft[(size_t)tid * MM + 2048].x;
    __syncthreads();

    const int g  = tid >> 5;
    const int ml = tid & 31;
    const int n  = nb + g;
    const float m0f = (float)(mb + ml);
    const float2* hcol = hft + mb + ml;

    float accm[4], accp[4];
#pragma unroll
    for (int k = 0; k < 4; ++k) { accm[k] = 0.0f; accp[k] = 0.0f; }

    float2 hA[4], hB[4], hC[4];
#pragma unroll
    for (int k = 0; k < 4; ++k) hA[k] = hcol[32 * k];              // d = 0
#pragma unroll
    for (int k = 0; k < 4; ++k) hB[k] = hcol[(size_t)MM + 32 * k]; // d = 1

#pragma unroll
    for (int d = 0; d < RR; ++d) {
        // static buffer selection (d is compile-time constant after unroll)
        float2* cur = (d % 3 == 0) ? hA : (d % 3 == 1) ? hB : hC;
        float2* nxt = ((d + 2) % 3 == 0) ? hA : ((d + 2) % 3 == 1) ? hB : hC;

        // issue depth-2 prefetch before consuming cur
        if (d + 2 < RR) {
            const float2* src = hcol + (size_t)(d + 2) * MM;
#pragma unroll
            for (int k = 0; k < 4; ++k) nxt[k] = src[32 * k];
        }

        const float A  = spw_s[g][d];
        const float tf = tf_s[g][d];
        const float ru = cu_s[g][d];
        const float iu = su_s[g][d];

        float r0 = tf * m0f;   r0 -= floorf(r0);
        float dl = tf * 32.0f; dl -= floorf(dl);
        const float c0 = __builtin_amdgcn_cosf(r0);
        const float s0 = __builtin_amdgcn_sinf(r0);
        const float cd = __builtin_amdgcn_cosf(dl);
        const float sd = __builtin_amdgcn_sinf(dl);
        float ca = A * c0, sa = A * s0;     // phasor (A folded in)

#pragma unroll
        for (int k = 0; k < 4; ++k) {
            const float2 h = cur[k];
            const float rz = fmaf(ca, h.x,   sa * h.y);
            const float iz = fmaf(ca, h.y, -(sa * h.x));
            accm[k] += rz;
            accp[k]  = fmaf(ru, rz, fmaf(iu, iz, accp[k]));
            if (k < 3) {
                const float can = fmaf(ca, cd, -(sa * sd));
                const float san = fmaf(sa, cd,  (ca * sd));
                ca = can; sa = san;
            }
        }
    }

    float* orow = out + (size_t)n * MM;
#pragma unroll
    for (int k = 0; k < 4; ++k) {
        const int m = mb + ml + 32 * k;       // [0, 2047]
        orow[m] = accm[k];
        if (m != 0) orow[MM - m] = accp[k];   // [2049, 4095]
    }

    // Nyquist column m = 2048 (real bin): one lane per row, bx==0 blocks.
    if (blockIdx.x == 0 && ml == 0) {
        float acc = 0.0f;
        for (int d = 0; d < RR; ++d) {
            float r = tf_s[g][d] * 2048.0f;
            r -= floorf(r);
            acc = fmaf(spw_s[g][d] * h2048_s[d], __builtin_amdgcn_cosf(r), acc);
        }
        orow[2048] = acc;
    }
}

// ---------------------------------------------------------------------------
// Complex-output hedge path (never taken in practice): R5-proven kernel.
// ---------------------------------------------------------------------------
__global__ __launch_bounds__(256) void shiftnmf_cplx(const float* __restrict__ W,
                                                     const float* __restrict__ tau,
                                                     const float2* __restrict__ hft,
                                                     float* __restrict__ out) {
    __shared__ float spw_s[16][RR];
    __shared__ float tau_s[16][RR];
    const int tid = threadIdx.x;
    const int mb  = blockIdx.x * 256;
    const int nb  = blockIdx.y * 16;
    for (int idx = tid; idx < 16 * RR; idx += 256) {
        const int nl = idx >> 5;
        const int dd = idx & 31;
        spw_s[nl][dd] = softplus_f(W[(size_t)(nb + nl) * RR + dd]);
        tau_s[nl][dd] = tau[(size_t)(nb + nl) * RR + dd] * (1.0f / (float)MM);
    }
    __syncthreads();
    const int g  = tid >> 5;
    const int ml = tid & 31;
    const int n0 = g * 2;
    const float m0f = (float)(mb + ml);
    const float2* hcol = hft + mb + ml;
    float accR[2][8], accI[2][8];
#pragma unroll
    for (int j = 0; j < 2; ++j)
#pragma unroll
        for (int k = 0; k < 8; ++k) { accR[j][k] = 0.0f; accI[j][k] = 0.0f; }
    float2 hc[8], hn[8];
#pragma unroll
    for (int k = 0; k < 8; ++k) hc[k] = hcol[32 * k];
    for (int d = 0; d < RR; ++d) {
        const float2* hnp = hcol + (size_t)((d + 1 < RR) ? d + 1 : d) * MM;
#pragma unroll
        for (int k = 0; k < 8; ++k) hn[k] = hnp[32 * k];
#pragma unroll
        for (int j = 0; j < 2; ++j) {
            const float A  = spw_s[n0 + j][d];
            const float tf = tau_s[n0 + j][d];
            float r0 = tf * m0f;  r0 -= floorf(r0);
            float dl = tf * 32.0f; dl -= floorf(dl);
            const float c0 = __builtin_amdgcn_cosf(r0);
            const float s0 = __builtin_amdgcn_sinf(r0);
            const float cd = __builtin_amdgcn_cosf(dl);
            const float sd = __builtin_amdgcn_sinf(dl);
            float ca = A * c0, sa = A * s0;
            float cb = ca * cd - sa * sd;
            float sb = sa * cd + ca * sd;
            const float c2 = fmaf(-2.0f * sd, sd, 1.0f);
            const float s2 = 2.0f * sd * cd;
#pragma unroll
            for (int t4 = 0; t4 < 4; ++t4) {
                const float2 h0 = hc[2 * t4];
                const float2 h1 = hc[2 * t4 + 1];
                accR[j][2*t4]   = fmaf(ca, h0.x, fmaf(sa, h0.y, accR[j][2*t4]));
                accR[j][2*t4+1] = fmaf(cb, h1.x, fmaf(sb, h1.y, accR[j][2*t4+1]));
                accI[j][2*t4]   = fmaf(ca, h0.y, fmaf(-sa, h0.x, accI[j][2*t4]));
                accI[j][2*t4+1] = fmaf(cb, h1.y, fmaf(-sb, h1.x, accI[j][2*t4+1]));
                if (t4 < 3) {
                    const float can = fmaf(ca, c2, -(sa * s2));
                    const float san = fmaf(sa, c2,  (ca * s2));
                    const float cbn = fmaf(cb, c2, -(sb * s2));
                    const float sbn = fmaf(sb, c2,  (cb * s2));
                    ca = can; sa = san; cb = cbn; sb = sbn;
                }
            }
        }
#pragma unroll
        for (int k = 0; k < 8; ++k) hc[k] = hn[k];
    }
#pragma unroll
    for (int j = 0; j < 2; ++j) {
        float2* orow = (float2*)out + (size_t)(nb + n0 + j) * MM + mb + ml;
#pragma unroll
        for (int k = 0; k < 8; ++k)
            orow[32 * k] = make_float2(accR[j][k], accI[j][k]);
    }
}

extern "C" void kernel_launch(void* const* d_in, const int* in_sizes, int n_in,
                              void* d_out, int out_size, void* d_ws, size_t ws_size,
                              hipStream_t stream) {
    const float* W   = (const float*)d_in[0];   // (512, 32)
    const float* H   = (const float*)d_in[1];   // (32, 4096)
    const float* tau = (const float*)d_in[2];   // (512, 32)

    const size_t hft_bytes = (size_t)RR * MM * sizeof(float2);  // 1 MB
    if (ws_size < 2 * hft_bytes) return;        // safe bail (no crash)
    float2* zbuf = (float2*)d_ws;               // step-1 intermediate (1 MB)
    float2* hft  = zbuf + (size_t)RR * MM;      // spectrum (1 MB)

    fft64_step1<<<512, 256, 0, stream>>>(H, zbuf);
    fft64_step2<<<512, 256, 0, stream>>>(zbuf, hft);

    if (out_size >= 2 * NN * MM) {
        dim3 grid(MM / 256, NN / 16);
        shiftnmf_cplx<<<grid, 256, 0, stream>>>(W, tau, hft, (float*)d_out);
    } else {
        dim3 grid(2048 / 128, NN / 8);
        shiftnmf_real<<<grid, 256, 0, stream>>>(W, tau, hft, (float*)d_out);
    }
}

// Round 11
// 31.550 us; speedup vs baseline: 4.2464x; 1.6244x over previous
//
#include <hip/hip_runtime.h>
#include <hip/hip_bf16.h>

#define MM 4096
#define NN 512
#define RR 32

__device__ __forceinline__ float softplus_f(float x) {
    return x > 20.0f ? x : log1pf(__expf(x));
}

__device__ __forceinline__ int bitrev6(int l) {
    return ((l & 1) << 5) | ((l & 2) << 3) | ((l & 4) << 1) |
           ((l & 8) >> 1) | ((l & 16) >> 3) | ((l & 32) >> 5);
}

// In-register 64-point DIF FFT across the 64 lanes of a wave.
__device__ __forceinline__ void wave_fft64(float& xr, float& xi) {
#pragma unroll
    for (int s = 32; s >= 1; s >>= 1) {
        const float pr = __shfl_xor(xr, s, 64);
        const float pi = __shfl_xor(xi, s, 64);
        const int   lane = threadIdx.x & 63;
        const bool  hi = (lane & s) != 0;
        const float ur = xr + pr, ui = xi + pi;
        const float vr = pr - xr, vi = pi - xi;
        const int   j  = lane & (s - 1);
        const float rev = (float)j * (1.0f / (float)(2 * s));   // [0, 0.5)
        const float ct = __builtin_amdgcn_cosf(rev);
        const float st = __builtin_amdgcn_sinf(rev);
        const float wr = fmaf(vr, ct,   vi * st);   // v * (ct - i st)
        const float wi = fmaf(vi, ct, -(vr * st));
        xr = hi ? wr : ur;
        xi = hi ? wi : ui;
    }
}

// ---------------------------------------------------------------------------
// FFT step 1 (proven): FFT-64 over n2, twiddle, transposed store.
// ---------------------------------------------------------------------------
__global__ __launch_bounds__(256) void fft64_step1(const float* __restrict__ H,
                                                   float2* __restrict__ zbuf) {
    const int wave = (blockIdx.x * 256 + threadIdx.x) >> 6;   // 0..2047
    const int lane = threadIdx.x & 63;                        // n2
    const int d    = wave >> 6;                               // 0..31
    const int n1   = wave & 63;                               // 0..63
    float xr = softplus_f(H[(size_t)d * MM + n1 + 64 * lane]);
    float xi = 0.0f;
    wave_fft64(xr, xi);
    const int k2 = bitrev6(lane);
    const float rev = (float)(n1 * k2) * (1.0f / 4096.0f);    // [0,1)
    const float ct = __builtin_amdgcn_cosf(rev);
    const float st = __builtin_amdgcn_sinf(rev);
    zbuf[(size_t)d * MM + k2 * 64 + n1] =
        make_float2(fmaf(xr, ct, xi * st), fmaf(xi, ct, -(xr * st)));
}

// ---------------------------------------------------------------------------
// FFT step 2 (proven): FFT-64 over n1 (contiguous), scatter.
// ---------------------------------------------------------------------------
__global__ __launch_bounds__(256) void fft64_step2(const float2* __restrict__ zbuf,
                                                   float2* __restrict__ hft) {
    const int wave = (blockIdx.x * 256 + threadIdx.x) >> 6;
    const int lane = threadIdx.x & 63;                        // n1
    const int d    = wave >> 6;
    const int k2   = wave & 63;
    const float2 z = zbuf[(size_t)d * MM + k2 * 64 + lane];
    float xr = z.x, xi = z.y;
    wave_fft64(xr, xi);
    hft[(size_t)d * MM + k2 + 64 * bitrev6(lane)] = make_float2(xr, xi);
}

// ---------------------------------------------------------------------------
// Main kernel: R6-proven K=8 dual-phasor Hermitian math, with 2-way
// d-stream interleaving (d and d+16) for ILP, ping-pong named register
// buffers (all statically indexed). Block: 8 rows x 32 lanes; 256-col
// tiles; grid (8, 64) = 512 blocks (2048 waves, 2/SIMD — wave count is
// fixed by work/thread; the lever here is ILP, not TLP).
// ---------------------------------------------------------------------------
__global__ __launch_bounds__(256) void shiftnmf_real(const float* __restrict__ W,
                                                     const float* __restrict__ tau,
                                                     const float2* __restrict__ hft,
                                                     float* __restrict__ out) {
    __shared__ float spw_s[8][RR];
    __shared__ float tf_s[8][RR];
    __shared__ float cu_s[8][RR];
    __shared__ float su_s[8][RR];
    __shared__ float h2048_s[RR];

    const int tid = threadIdx.x;
    const int mb  = blockIdx.x * 256;      // [0, 2048)
    const int nb  = blockIdx.y * 8;

    {
        const int nl = tid >> 5;
        const int dd = tid & 31;
        const float w = W[(size_t)(nb + nl) * RR + dd];
        const float t = tau[(size_t)(nb + nl) * RR + dd];
        spw_s[nl][dd] = softplus_f(w);
        tf_s[nl][dd]  = t * (1.0f / (float)MM);
        const float fr = t - floorf(t);                // frac(tau)
        cu_s[nl][dd] =  __builtin_amdgcn_cosf(fr);     // Re e^{-2pi i tau}
        su_s[nl][dd] = -__builtin_amdgcn_sinf(fr);     // Im e^{-2pi i tau}
    }
    if (tid < RR) h2048_s[tid] = hft[(size_t)tid * MM + 2048].x;
    __syncthreads();

    const int g  = tid >> 5;
    const int ml = tid & 31;
    const int n  = nb + g;
    const float m0f = (float)(mb + ml);
    const float2* hcol = hft + mb + ml;

    float accm[8], accp[8];
#pragma unroll
    for (int k = 0; k < 8; ++k) { accm[k] = 0.0f; accp[k] = 0.0f; }

    float2 A0[8], A1[8], B0[8], B1[8];

#define LOADROW(DST, ROW)                                                   \
    _Pragma("unroll")                                                       \
    for (int k = 0; k < 8; ++k) DST[k] = hcol[(size_t)(ROW) * MM + 32 * k];

    // R6-proven dual-phasor Hermitian body for one d, reading HB[0..7].
#define COMPUTE(DD, HB)                                                     \
    {                                                                       \
        const int d_ = (DD);                                                \
        const float A  = spw_s[g][d_];                                      \
        const float tf = tf_s[g][d_];                                       \
        const float ru = cu_s[g][d_];                                       \
        const float iu = su_s[g][d_];                                       \
        float r0 = tf * m0f;   r0 -= floorf(r0);                            \
        float dl = tf * 32.0f; dl -= floorf(dl);                            \
        const float c0 = __builtin_amdgcn_cosf(r0);                         \
        const float s0 = __builtin_amdgcn_sinf(r0);                         \
        const float cd = __builtin_amdgcn_cosf(dl);                         \
        const float sd = __builtin_amdgcn_sinf(dl);                         \
        float ca = A * c0, sa = A * s0;                                     \
        float cb = ca * cd - sa * sd;                                       \
        float sb = sa * cd + ca * sd;                                       \
        const float c2 = fmaf(-2.0f * sd, sd, 1.0f);                        \
        const float s2 = 2.0f * sd * cd;                                    \
        _Pragma("unroll")                                                   \
        for (int t = 0; t < 4; ++t) {                                       \
            const float2 h0 = HB[2 * t];                                    \
            const float2 h1 = HB[2 * t + 1];                                \
            {                                                               \
                const float rz = fmaf(ca, h0.x,   sa * h0.y);               \
                const float iz = fmaf(ca, h0.y, -(sa * h0.x));              \
                accm[2 * t] += rz;                                          \
                accp[2 * t]  = fmaf(ru, rz, fmaf(iu, iz, accp[2 * t]));     \
            }                                                               \
            {                                                               \
                const float rz = fmaf(cb, h1.x,   sb * h1.y);               \
                const float iz = fmaf(cb, h1.y, -(sb * h1.x));              \
                accm[2 * t + 1] += rz;                                      \
                accp[2 * t + 1]  = fmaf(ru, rz, fmaf(iu, iz, accp[2 * t + 1])); \
            }                                                               \
            if (t < 3) {                                                    \
                const float can = fmaf(ca, c2, -(sa * s2));                 \
                const float san = fmaf(sa, c2,  (ca * s2));                 \
                const float cbn = fmaf(cb, c2, -(sb * s2));                 \
                const float sbn = fmaf(sb, c2,  (cb * s2));                 \
                ca = can; sa = san; cb = cbn; sb = sbn;                     \
            }                                                               \
        }                                                                   \
    }

    LOADROW(A0, 0)        // d = 0 (stream A)
    LOADROW(B0, 16)       // d = 16 (stream B)

    for (int i = 0; i < 16; i += 2) {
        if (i + 1 < 16) { LOADROW(A1, i + 1) LOADROW(B1, i + 17) }
        COMPUTE(i,      A0)
        COMPUTE(i + 16, B0)
        if (i + 2 < 16) { LOADROW(A0, i + 2) LOADROW(B0, i + 18) }
        COMPUTE(i + 1,  A1)
        COMPUTE(i + 17, B1)
    }
#undef LOADROW
#undef COMPUTE

    float* orow = out + (size_t)n * MM;
#pragma unroll
    for (int k = 0; k < 8; ++k) {
        const int m = mb + ml + 32 * k;       // [0, 2047]
        orow[m] = accm[k];
        if (m != 0) orow[MM - m] = accp[k];   // [2049, 4095]
    }

    // Nyquist column m = 2048 (real bin): one lane per row, bx==0 blocks.
    if (blockIdx.x == 0 && ml == 0) {
        float acc = 0.0f;
        for (int d = 0; d < RR; ++d) {
            float r = tf_s[g][d] * 2048.0f;
            r -= floorf(r);
            acc = fmaf(spw_s[g][d] * h2048_s[d], __builtin_amdgcn_cosf(r), acc);
        }
        orow[2048] = acc;
    }
}

// ---------------------------------------------------------------------------
// Complex-output hedge path (never taken in practice): R5-proven kernel.
// ---------------------------------------------------------------------------
__global__ __launch_bounds__(256) void shiftnmf_cplx(const float* __restrict__ W,
                                                     const float* __restrict__ tau,
                                                     const float2* __restrict__ hft,
                                                     float* __restrict__ out) {
    __shared__ float spw_s[16][RR];
    __shared__ float tau_s[16][RR];
    const int tid = threadIdx.x;
    const int mb  = blockIdx.x * 256;
    const int nb  = blockIdx.y * 16;
    for (int idx = tid; idx < 16 * RR; idx += 256) {
        const int nl = idx >> 5;
        const int dd = idx & 31;
        spw_s[nl][dd] = softplus_f(W[(size_t)(nb + nl) * RR + dd]);
        tau_s[nl][dd] = tau[(size_t)(nb + nl) * RR + dd] * (1.0f / (float)MM);
    }
    __syncthreads();
    const int g  = tid >> 5;
    const int ml = tid & 31;
    const int n0 = g * 2;
    const float m0f = (float)(mb + ml);
    const float2* hcol = hft + mb + ml;
    float accR[2][8], accI[2][8];
#pragma unroll
    for (int j = 0; j < 2; ++j)
#pragma unroll
        for (int k = 0; k < 8; ++k) { accR[j][k] = 0.0f; accI[j][k] = 0.0f; }
    float2 hc[8], hn[8];
#pragma unroll
    for (int k = 0; k < 8; ++k) hc[k] = hcol[32 * k];
    for (int d = 0; d < RR; ++d) {
        const float2* hnp = hcol + (size_t)((d + 1 < RR) ? d + 1 : d) * MM;
#pragma unroll
        for (int k = 0; k < 8; ++k) hn[k] = hnp[32 * k];
#pragma unroll
        for (int j = 0; j < 2; ++j) {
            const float A  = spw_s[n0 + j][d];
            const float tf = tau_s[n0 + j][d];
            float r0 = tf * m0f;  r0 -= floorf(r0);
            float dl = tf * 32.0f; dl -= floorf(dl);
            const float c0 = __builtin_amdgcn_cosf(r0);
            const float s0 = __builtin_amdgcn_sinf(r0);
            const float cd = __builtin_amdgcn_cosf(dl);
            const float sd = __builtin_amdgcn_sinf(dl);
            float ca = A * c0, sa = A * s0;
            float cb = ca * cd - sa * sd;
            float sb = sa * cd + ca * sd;
            const float c2 = fmaf(-2.0f * sd, sd, 1.0f);
            const float s2 = 2.0f * sd * cd;
#pragma unroll
            for (int t4 = 0; t4 < 4; ++t4) {
                const float2 h0 = hc[2 * t4];
                const float2 h1 = hc[2 * t4 + 1];
                accR[j][2*t4]   = fmaf(ca, h0.x, fmaf(sa, h0.y, accR[j][2*t4]));
                accR[j][2*t4+1] = fmaf(cb, h1.x, fmaf(sb, h1.y, accR[j][2*t4+1]));
                accI[j][2*t4]   = fmaf(ca, h0.y, fmaf(-sa, h0.x, accI[j][2*t4]));
                accI[j][2*t4+1] = fmaf(cb, h1.y, fmaf(-sb, h1.x, accI[j][2*t4+1]));
                if (t4 < 3) {
                    const float can = fmaf(ca, c2, -(sa * s2));
                    const float san = fmaf(sa, c2,  (ca * s2));
                    const float cbn = fmaf(cb, c2, -(sb * s2));
                    const float sbn = fmaf(sb, c2,  (cb * s2));
                    ca = can; sa = san; cb = cbn; sb = sbn;
                }
            }
        }
#pragma unroll
        for (int k = 0; k < 8; ++k) hc[k] = hn[k];
    }
#pragma unroll
    for (int j = 0; j < 2; ++j) {
        float2* orow = (float2*)out + (size_t)(nb + n0 + j) * MM + mb + ml;
#pragma unroll
        for (int k = 0; k < 8; ++k)
            orow[32 * k] = make_float2(accR[j][k], accI[j][k]);
    }
}

extern "C" void kernel_launch(void* const* d_in, const int* in_sizes, int n_in,
                              void* d_out, int out_size, void* d_ws, size_t ws_size,
                              hipStream_t stream) {
    const float* W   = (const float*)d_in[0];   // (512, 32)
    const float* H   = (const float*)d_in[1];   // (32, 4096)
    const float* tau = (const float*)d_in[2];   // (512, 32)

    const size_t hft_bytes = (size_t)RR * MM * sizeof(float2);  // 1 MB
    if (ws_size < 2 * hft_bytes) return;        // safe bail (no crash)
    float2* zbuf = (float2*)d_ws;               // step-1 intermediate (1 MB)
    float2* hft  = zbuf + (size_t)RR * MM;      // spectrum (1 MB)

    fft64_step1<<<512, 256, 0, stream>>>(H, zbuf);
    fft64_step2<<<512, 256, 0, stream>>>(zbuf, hft);

    if (out_size >= 2 * NN * MM) {
        dim3 grid(MM / 256, NN / 16);
        shiftnmf_cplx<<<grid, 256, 0, stream>>>(W, tau, hft, (float*)d_out);
    } else {
        dim3 grid(2048 / 256, NN / 8);
        shiftnmf_real<<<grid, 256, 0, stream>>>(W, tau, hft, (float*)d_out);
    }
}